// Round 7
// baseline (97.663 us; speedup 1.0000x reference)
//
#include <hip/hip_runtime.h>
#include <stdint.h>

typedef __attribute__((ext_vector_type(4))) float f32x4;
typedef __attribute__((ext_vector_type(4))) unsigned int u32x4;
typedef __attribute__((ext_vector_type(2))) long long i64x2;
typedef long long i64_t;

#define NB 16
#define NC 128
#define NH 128
#define NW 128
#define HP 130
#define WP 130

typedef const __attribute__((address_space(1))) void gv_t;
typedef __attribute__((address_space(3))) void lv_t;
__device__ __forceinline__ void gload16(const void* g, void* l) {
    __builtin_amdgcn_global_load_lds((gv_t*)g, (lv_t*)l, 16, 0, 0);
}

// ---------------- prep: wfrag (B sign bytes) + sf = mean|w| ----------------
// wfrag flat byte f = p*8192 + kb*2048 + nip*1024 + l*16 + nl*8 + j   (ni = nip*2+nl)
// o = ni*16 + (l&15)
// K relabeling for plain-SB A-fragments: instr kb, lane lg holds 8-block
// {2lg,2lg+1,2lg+8,2lg+9}[kb]  ->  c = lg*16 + (kb&1)*8 + (kb>>1)*64 + j
__global__ __launch_bounds__(256) void k_prep(const float* __restrict__ cw,
                                              float* __restrict__ sf,
                                              unsigned char* __restrict__ wf) {
    int b = blockIdx.x, t = threadIdx.x;    // 288 blocks
    int f = b * 256 + t;                    // < 73728
    int j   = f & 7;
    int nl  = (f >> 3) & 1;
    int l   = (f >> 4) & 63;
    int nip = (f >> 10) & 1;
    int kb  = (f >> 11) & 3;
    int p   = f >> 13;
    int o = (nip * 2 + nl) * 16 + (l & 15);
    int lg = (l >> 4) & 3;
    int c = lg * 16 + (kb & 1) * 8 + (kb >> 1) * 64 + j;   // NEW plain-unit K mapping
    float wv = cw[o * 1152 + c * 9 + p];
    wf[f] = wv > 0.f ? (unsigned char)0x38
                     : (wv < 0.f ? (unsigned char)0xB8 : (unsigned char)0x00);
    if (b < 64) {                           // sf[b] = mean|w| over 1152
        __shared__ float red[4];
        const float* pp = cw + b * 1152;
        float s = 0.f;
        for (int i = t; i < 1152; i += 256) s += fabsf(pp[i]);
#pragma unroll
        for (int off = 32; off > 0; off >>= 1) s += __shfl_down(s, off);
        if ((t & 63) == 0) red[t >> 6] = s;
        __syncthreads();
        if (t == 0) sf[b] = (red[0] + red[1] + red[2] + red[3]) * (1.0f / 1152.0f);
    }
}

__device__ __forceinline__ unsigned int sgn8(float v, float b1v, float av, float b2v) {
    float t = v + b1v;
    t = fmaxf(t, 0.f) + av * fminf(t, 0.f);
    t += b2v;
    return t > 0.f ? 0x38u : (t < 0.f ? 0xB8u : 0u);
}

// ---------------- k1: activation signs -> SB (padded NHWC fp8, PLAIN layout),
//                  shortcut -> out.  ROUND-2-VERBATIM (the 33 us version). ----------------
__global__ __launch_bounds__(256) void k1_signs_shortcut(
    const float* __restrict__ x, const float* __restrict__ b1,
    const float* __restrict__ pa, const float* __restrict__ b2,
    const float* __restrict__ pw, unsigned char* __restrict__ SB,
    float* __restrict__ out) {
    __shared__ unsigned short T[128][65];   // [w][o] ; packs fp8 of c=2o (lo byte), 2o+1 (hi)
    int bx = blockIdx.x;                    // 16*130
    int nb = bx / 130;
    int hp = bx % 130;
    unsigned char* sbrow = SB + ((size_t)nb * HP + hp) * WP * NC;
    int t = threadIdx.x;
    if (hp == 0 || hp == HP - 1) {          // zero pad rows (16640 B)
        u32x4 z = {0u, 0u, 0u, 0u};
        for (int i = t; i < WP * NC / 16; i += 256)
            ((u32x4*)sbrow)[i] = z;
        return;
    }
    int h = hp - 1;
    int wp2 = t & 63;                       // w pair index: w = 2*wp2, 2*wp2+1
    int oq = t >> 6;                        // 0..3
    const float* xb = x + ((size_t)nb * NC) * NH * NW + (size_t)h * NW + 2 * wp2;
    int s1 = h & 1, h2 = h >> 1;
    float* ob = out + (((size_t)nb * 256 + s1 * 2) * 64 + h2) * 64 + wp2;
#pragma unroll 4
    for (int i = 0; i < 16; ++i) {
        int o = oq * 16 + i;
        int c0 = 2 * o, c1 = c0 + 1;
        float2 x0 = *(const float2*)(xb + (size_t)c0 * NH * NW);
        float2 x1 = *(const float2*)(xb + (size_t)c1 * NH * NW);
        float b10 = b1[c0], b11 = b1[c1];
        float pa0 = pa[c0], pa1 = pa[c1];
        float b20 = b2[c0], b21 = b2[c1];
        unsigned int lo0 = sgn8(x0.x, b10, pa0, b20);
        unsigned int hi0 = sgn8(x1.x, b11, pa1, b21);
        unsigned int lo1 = sgn8(x0.y, b10, pa0, b20);
        unsigned int hi1 = sgn8(x1.y, b11, pa1, b21);
        T[2 * wp2][o]     = (unsigned short)(lo0 | (hi0 << 8));
        T[2 * wp2 + 1][o] = (unsigned short)(lo1 | (hi1 << 8));
        float w0v = pw[c0], w1v = pw[c1];
        ob[(size_t)o * 16384]        = w0v * x0.x + w1v * x1.x;   // s2=0
        ob[(size_t)o * 16384 + 4096] = w0v * x0.y + w1v * x1.y;   // s2=1
    }
    __syncthreads();
    if (t < 32) {                           // zero pad cols wp=0 and wp=129 (128 B each)
        int k = t & 15, side = t >> 4;
        uint2 z = {0u, 0u};
        *(uint2*)(sbrow + (side ? (size_t)(WP - 1) * NC : (size_t)0) + k * 8) = z;
    }
#pragma unroll
    for (int pp = 0; pp < 8; ++pp) {        // transposed writeback, plain c-contiguous
        int wloc = pp * 16 + (t >> 4);
        int k = t & 15;
        unsigned int t0 = T[wloc][4 * k + 0];
        unsigned int t1 = T[wloc][4 * k + 1];
        unsigned int t2 = T[wloc][4 * k + 2];
        unsigned int t3 = T[wloc][4 * k + 3];
        uint2 v;
        v.x = t0 | (t1 << 16);              // channels 8k..8k+3
        v.y = t2 | (t3 << 16);              // channels 8k+4..8k+7
        *(uint2*)(sbrow + (size_t)(wloc + 1) * NC + k * 8) = v;
    }
}

// ---------------- k2: implicit-GEMM binary conv; A-tile in LDS via DMA with
//                  per-lane inverse-swizzled SOURCE (plain SB -> swizzled LDS) ----------------
__global__ __launch_bounds__(256, 2) void k2_conv(
    const unsigned char* __restrict__ SB, const unsigned char* __restrict__ wf,
    const float* __restrict__ sf, float* __restrict__ out) {
    __shared__ __align__(16) unsigned char AT[66560];   // 4 padded rows x 130 x 128B
    int bxr = blockIdx.x;
    int bx = (bxr & 7) * 128 + (bxr >> 3);  // XCD swizzle (1024 % 8 == 0, bijective)
    int nb = bx >> 6;
    int h2b = bx & 63;
    int t = threadIdx.x;
    int wid = t >> 6;
    int l = t & 63;
    int lr = l & 15, lg = l >> 4;
    // staging: LDS slot u of column wp  <-  plain-SB unit u^(wp&7)  (16B units)
    // loop (rho, blk): dest unit = rho*1040 + blk*256 + t; wp&7 = (t>>3)&7 per-thread const
    const unsigned char* gsrc = SB + ((size_t)nb * HP + 2 * h2b) * (WP * NC);
    int srcdelta = ((((t & 7) ^ ((t >> 3) & 7)) - (t & 7)) << 4);
#pragma unroll
    for (int rho = 0; rho < 4; ++rho) {
#pragma unroll
        for (int blk = 0; blk < 5; ++blk) {
            int d = rho * 1040 + blk * 256;
            if (blk < 4 || (t >> 3) < 2)    // tail: wp 128,129 only
                gload16(gsrc + (size_t)(d + t) * 16 + srcdelta,
                        AT + (d + wid * 64) * 16);
        }
    }

    int h = h2b * 2 + (wid >> 1);           // output row for this wave
    int w0 = (wid & 1) * 64;                // output col base
    f32x4 acc[4][4];
    f32x4 zero = {0.f, 0.f, 0.f, 0.f};
#pragma unroll
    for (int mi = 0; mi < 4; ++mi)
#pragma unroll
        for (int ni = 0; ni < 4; ++ni) acc[mi][ni] = zero;
    __syncthreads();

#pragma unroll
    for (int p = 0; p < 9; ++p) {
        int kh = p / 3, kw = p % 3;         // constants after unroll
        int rho = (wid >> 1) + kh;          // local padded row 0..3
        int wp = w0 + kw + lr;
        int sb7 = wp & 7;
        const unsigned char* ap = AT + (size_t)(rho * WP + wp) * NC;
        const unsigned char* brow = wf + p * 8192 + l * 16;
        i64_t bfr[4][4];
#pragma unroll
        for (int kb = 0; kb < 4; ++kb) {    // B: 16B/lane coalesced, L2-hot
            i64x2 b01 = *(const i64x2*)(brow + kb * 2048);
            i64x2 b23 = *(const i64x2*)(brow + kb * 2048 + 1024);
            bfr[kb][0] = b01.x; bfr[kb][1] = b01.y;
            bfr[kb][2] = b23.x; bfr[kb][3] = b23.y;
        }
        int off0 = (lg ^ sb7) << 4;         // logical unit lg   (K-blocks 2lg, 2lg+1)
        int off1 = ((lg + 4) ^ sb7) << 4;   // logical unit lg+4 (K-blocks 2lg+8, 2lg+9)
#pragma unroll
        for (int mi = 0; mi < 4; ++mi) {    // 2 x ds_read_b128 = all 4 kb fragments
            i64x2 a01 = *(const i64x2*)(ap + mi * 2048 + off0);
            i64x2 a23 = *(const i64x2*)(ap + mi * 2048 + off1);
            i64_t af[4] = {a01.x, a01.y, a23.x, a23.y};
#pragma unroll
            for (int kb = 0; kb < 4; ++kb)
#pragma unroll
                for (int ni = 0; ni < 4; ++ni)
                    acc[mi][ni] = __builtin_amdgcn_mfma_f32_16x16x32_fp8_fp8(
                        af[kb], bfr[kb][ni], acc[mi][ni], 0, 0, 0);
        }
    }
    __syncthreads();                        // A-tile dead; reuse LDS for epilogue transpose
    float (*Tt)[33] = (float (*)[33])(AT + wid * 8448);
    int s1 = h & 1, h2 = h >> 1;
    float* ob = out + (((size_t)nb * 256 + s1 * 2) * 64 + h2) * 64;
    int og = l >> 5;
    int wl_lo = l & 31;
#pragma unroll
    for (int half = 0; half < 2; ++half) {
#pragma unroll
        for (int mi2 = 0; mi2 < 2; ++mi2) {
            int mi = half * 2 + mi2;
#pragma unroll
            for (int ni = 0; ni < 4; ++ni)
#pragma unroll
                for (int r = 0; r < 4; ++r)
                    Tt[ni * 16 + lr][mi2 * 16 + lg * 4 + r] = acc[mi][ni][r];
        }
        asm volatile("" ::: "memory");      // per-wave DS in-order; pin compiler order
        int w = w0 + half * 32 + wl_lo;
        int lanoff = (w & 1) * 4096 + (w >> 1);
        for (int oo = 0; oo < 32; ++oo) {
            int o = 2 * oo + og;
            ob[(size_t)o * 16384 + lanoff] += Tt[o][wl_lo] * sf[o];
        }
        asm volatile("" ::: "memory");      // WAR: half 1 writes after half 0 reads
    }
}

extern "C" void kernel_launch(void* const* d_in, const int* in_sizes, int n_in,
                              void* d_out, int out_size, void* d_ws, size_t ws_size,
                              hipStream_t stream) {
    const float* x  = (const float*)d_in[0];
    const float* b1 = (const float*)d_in[1];
    const float* pa = (const float*)d_in[2];
    const float* b2 = (const float*)d_in[3];
    const float* cw = (const float*)d_in[4];
    const float* pw = (const float*)d_in[5];
    float* out = (float*)d_out;
    // ws layout: [0,256) sf | [256, 256+73728) wfrag fp8 | then SB (plain NHWC fp8, ~34.6 MB)
    float* sf = (float*)d_ws;
    unsigned char* wfr = (unsigned char*)d_ws + 256;
    unsigned char* SB  = (unsigned char*)d_ws + 256 + 73728;

    k_prep<<<288, 256, 0, stream>>>(cw, sf, wfr);
    k1_signs_shortcut<<<NB * HP, 256, 0, stream>>>(x, b1, pa, b2, pw, SB, out);
    k2_conv<<<1024, 256, 0, stream>>>(SB, wfr, sf, out);
}